// Round 9
// baseline (134.247 us; speedup 1.0000x reference)
//
#include <hip/hip_runtime.h>
#include <hip/hip_bf16.h>

#define Hh   200
#define Ww   200
#define CIN  490
#define OCN  98      // 2*K*K
#define KK   7
#define COUT 10
#define NROIS 512
#define PIX  8

#define PH   202     // padded H
#define PW   202     // padded W
#define PC   512     // padded channels
#define NPIX (Hh * Ww)          // 40000
#define NT   4                  // N tiles of 32 (128 cols, 98 real)
#define NU32 288                // 32 kc16 * 9 taps (kc-major: u = kc16*9 + tap)
#define NG32 72                 // 288 / 4 units per granule

typedef __attribute__((ext_vector_type(8))) short short8;
typedef __attribute__((ext_vector_type(4))) float float4v;
typedef __attribute__((ext_vector_type(16))) float float16v;

// ---------------------------------------------------------------------------
// Pack features fp32 [200,200,490] -> bf16 [202,202,512], zero borders+pad.
// ---------------------------------------------------------------------------
__global__ __launch_bounds__(256) void pack_feat_kernel(
    const float* __restrict__ feat, __hip_bfloat16* __restrict__ pf)
{
    int tid = blockIdx.x * 256 + threadIdx.x;
    if (tid >= PH * PW * (PC / 8)) return;
    int c8  = (tid & 63) * 8;
    int pix = tid >> 6;
    int py = pix / PW, px = pix % PW;
    __hip_bfloat16* dst = pf + (size_t)pix * PC + c8;
    bool interior = (py >= 1 && py <= Hh && px >= 1 && px <= Ww);

    __hip_bfloat16 v[8];
    if (interior && c8 + 8 <= CIN) {
        const float* s = feat + ((size_t)(py - 1) * Ww + (px - 1)) * CIN + c8;
#pragma unroll
        for (int q = 0; q < 4; ++q) {
            float2 f2 = *reinterpret_cast<const float2*>(s + q * 2);
            v[q * 2]     = __float2bfloat16(f2.x);
            v[q * 2 + 1] = __float2bfloat16(f2.y);
        }
    } else {
        const float* s = interior ? feat + ((size_t)(py - 1) * Ww + (px - 1)) * CIN : nullptr;
#pragma unroll
        for (int j = 0; j < 8; ++j) {
            float val = (interior && (c8 + j) < CIN) ? s[c8 + j] : 0.f;
            v[j] = __float2bfloat16(val);
        }
    }
    *reinterpret_cast<short8*>(dst) = *reinterpret_cast<short8*>(v);
}

// ---------------------------------------------------------------------------
// Pack weights fp32 [3,3,490,98] -> bf16 in 32x32x16 MFMA B-fragment order,
// kc-major: bp[u][t][lane][j], u = kc16*9 + tap, with
// k = kc16*16 + (lane>>5)*8 + j, n = t*32 + (lane&31);
// zero-padded for k>=490 or n>=98.
// ---------------------------------------------------------------------------
__global__ __launch_bounds__(256) void pack_w_kernel(
    const float* __restrict__ w, __hip_bfloat16* __restrict__ bp)
{
    int idx = blockIdx.x * 256 + threadIdx.x;
    if (idx >= NU32 * NT * 64 * 8) return;
    int j = idx & 7;
    int l = (idx >> 3) & 63;
    int t = (idx >> 9) & 3;
    int u = idx >> 11;               // 0..287, u = kc16*9 + tap
    int kc = u / 9, tap = u % 9;
    int k = kc * 16 + ((l >> 5) * 8) + j;
    int n = t * 32 + (l & 31);
    float val = (k < CIN && n < OCN) ? w[((size_t)tap * CIN + k) * OCN + n] : 0.f;
    bp[idx] = __float2bfloat16(val);
}

// ---------------------------------------------------------------------------
// Implicit-GEMM 3x3 conv via 32x32x16 MFMA with LDS-shared B.
// Block = 640 threads (10 waves) = 5 mpos x 2 nh; block M = 160; grid = 250.
// Wave = M=32 x N=64 (2 of 4 N-tiles). One 16B B ds_read -> one 32x32x16
// MFMA (32768 FLOP) = 2x FLOP/LDS-byte vs 16x16x32 at MR=1 -> LDS-read
// traffic halves at identical occupancy/balance and LOW register pressure
// (r5/r8 spilled at MR=2; this stays ~100 VGPR).
// Units kc-major (u = kc16*9 + tap) for the r7 cache-locality win.
// B double-buffered: granule = 4 units x 4 KB, ring of 8 slots = 32 KB.
// B reg-staged issue-early/write-late; A prefetched one granule ahead.
// ---------------------------------------------------------------------------
__global__ __launch_bounds__(640) void conv_mfma_kernel(
    const short* __restrict__ pf,   // padfeat bf16 [202*202*512]
    const short* __restrict__ bp,   // bpack bf16 [288*4*64*8]
    float* __restrict__ om)         // [40000,98]
{
    __shared__ short bsm[8 * 2048];  // 8 unit-slots x 4096 B = 32,768 B

    int l = threadIdx.x & 63;
    int w = threadIdx.x >> 6;        // wave 0..9
    int nh = w & 1;                  // N-half: tiles {0,1} or {2,3}
    int m0 = blockIdx.x * 160 + (w >> 1) * 32;

    int row = m0 + (l & 31);
    int y = row / Ww, x = row % Ww;
    const short* abase = pf + ((size_t)(y * PW + x) * PC) + ((l >> 5) * 8);

    float16v acc0 = {0.f,0.f,0.f,0.f,0.f,0.f,0.f,0.f,0.f,0.f,0.f,0.f,0.f,0.f,0.f,0.f};
    float16v acc1 = {0.f,0.f,0.f,0.f,0.f,0.f,0.f,0.f,0.f,0.f,0.f,0.f,0.f,0.f,0.f,0.f};

    // A offset (in shorts) for k-unit u = kc16*9 + tap
    auto aOff = [&](int u) -> int {
        int kc = u / 9, tap = u - kc * 9;
        int ky = tap / 3, kx = tap - ky * 3;
        return (ky * PW + kx) * PC + kc * 16;
    };

    // ---- prologue: stage granule 0 (units 0..3 x 4 tiles = 16 slot-writes) --
#pragma unroll
    for (int s = 0; s < 2; ++s) {
        int i = w + s * 10;
        if (i < 16) {
            int uu = i >> 2, t = i & 3;
            short8 v = *reinterpret_cast<const short8*>(
                bp + ((size_t)(uu * NT + t)) * 512 + l * 8);
            *reinterpret_cast<short8*>(&bsm[(uu & 7) * 2048 + t * 512 + l * 8]) = v;
        }
    }
    // prefetch A for granule 0
    short8 a0 = *reinterpret_cast<const short8*>(abase + aOff(0));
    short8 a1 = *reinterpret_cast<const short8*>(abase + aOff(1));
    short8 a2 = *reinterpret_cast<const short8*>(abase + aOff(2));
    short8 a3 = *reinterpret_cast<const short8*>(abase + aOff(3));
    __syncthreads();

    for (int g = 0; g < NG32; ++g) {
        bool more = (g < NG32 - 1);
        int u0n = (g + 1) * 4;

        // 1) issue B global loads for granule g+1 (regs, named slots)
        short8 st0, st1;
        int off0 = -1, off1 = -1;
        if (more) {
            {
                int i = w;                 // < 10, always < 16
                int uu = u0n + (i >> 2), t = i & 3;
                st0 = *reinterpret_cast<const short8*>(
                    bp + ((size_t)(uu * NT + t)) * 512 + l * 8);
                off0 = (uu & 7) * 2048 + t * 512 + l * 8;
            }
            if (w + 10 < 16) {
                int i = w + 10;
                int uu = u0n + (i >> 2), t = i & 3;
                st1 = *reinterpret_cast<const short8*>(
                    bp + ((size_t)(uu * NT + t)) * 512 + l * 8);
                off1 = (uu & 7) * 2048 + t * 512 + l * 8;
            }
        }
        // 2) issue A loads for granule g+1
        short8 n0, n1, n2, n3;
        if (more) {
            n0 = *reinterpret_cast<const short8*>(abase + aOff(u0n + 0));
            n1 = *reinterpret_cast<const short8*>(abase + aOff(u0n + 1));
            n2 = *reinterpret_cast<const short8*>(abase + aOff(u0n + 2));
            n3 = *reinterpret_cast<const short8*>(abase + aOff(u0n + 3));
        }

        // 3) compute granule g: 4 units x 2 tiles (this wave's N-half)
        int u0 = g * 4;
#define COMPUTE_UNIT(J, AREG)                                                   \
        {                                                                       \
            int sbase = ((u0 + J) & 7) * 2048 + nh * 1024 + l * 8;              \
            short8 b0 = *reinterpret_cast<short8*>(&bsm[sbase]);                \
            short8 b1 = *reinterpret_cast<short8*>(&bsm[sbase + 512]);          \
            acc0 = __builtin_amdgcn_mfma_f32_32x32x16_bf16(AREG, b0, acc0, 0, 0, 0); \
            acc1 = __builtin_amdgcn_mfma_f32_32x32x16_bf16(AREG, b1, acc1, 0, 0, 0); \
        }
        COMPUTE_UNIT(0, a0)
        COMPUTE_UNIT(1, a1)
        COMPUTE_UNIT(2, a2)
        COMPUTE_UNIT(3, a3)
#undef COMPUTE_UNIT

        // 4) write staged B to LDS
        if (off0 >= 0) *reinterpret_cast<short8*>(&bsm[off0]) = st0;
        if (off1 >= 0) *reinterpret_cast<short8*>(&bsm[off1]) = st1;
        // 5) rotate A prefetch
        if (more) { a0 = n0; a1 = n1; a2 = n2; a3 = n3; }
        __syncthreads();
    }

    // epilogue: store C. D layout: col=lane&31, row=(reg&3)+8*(reg>>2)+4*(lane>>5)
    int col_lo = l & 31;
    int rbase = m0 + 4 * (l >> 5);
#pragma unroll
    for (int tt = 0; tt < 2; ++tt) {
        int col = (nh * 2 + tt) * 32 + col_lo;
        if (col < OCN) {
            const float16v& A = tt ? acc1 : acc0;
#pragma unroll
            for (int reg = 0; reg < 16; ++reg) {
                int r = rbase + (reg & 3) + 8 * (reg >> 2);
                om[(size_t)r * OCN + col] = A[reg];
            }
        }
    }
}

// ---------------------------------------------------------------------------
// Fallback fp32 conv (used only if ws too small for the MFMA path).
// ---------------------------------------------------------------------------
__global__ __launch_bounds__(256) void conv3x3_kernel(
    const float* __restrict__ feat, const float* __restrict__ w,
    const float* __restrict__ zero, float* __restrict__ om)
{
    int idx = blockIdx.x * blockDim.x + threadIdx.x;
    if (idx >= Hh * (Ww / PIX) * OCN) return;
    int oc = idx % OCN;
    int g  = idx / OCN;
    int x0 = (g % (Ww / PIX)) * PIX;
    int y  = g / (Ww / PIX);

    float acc[PIX];
#pragma unroll
    for (int p = 0; p < PIX; ++p) acc[p] = 0.f;

    for (int ky = 0; ky < 3; ++ky) {
        int yy = y + ky - 1;
        if (yy < 0 || yy >= Hh) continue;
        const float* frow = feat + (size_t)yy * Ww * CIN;
        for (int kx = 0; kx < 3; ++kx) {
            const float* wp = w + ((ky * 3 + kx) * CIN) * OCN + oc;
            const float* fp[PIX];
#pragma unroll
            for (int p = 0; p < PIX; ++p) {
                int xx = x0 + p + kx - 1;
                fp[p] = (xx >= 0 && xx < Ww) ? (frow + (size_t)xx * CIN) : zero;
            }
            for (int ic = 0; ic < CIN; ic += 2) {
                float w0 = wp[ic * OCN];
                float w1 = wp[(ic + 1) * OCN];
#pragma unroll
                for (int p = 0; p < PIX; ++p) {
                    float2 f = *reinterpret_cast<const float2*>(fp[p] + ic);
                    acc[p] = fmaf(f.x, w0, acc[p]);
                    acc[p] = fmaf(f.y, w1, acc[p]);
                }
            }
        }
    }
    float* orow = om + ((size_t)y * Ww + x0) * OCN + oc;
#pragma unroll
    for (int p = 0; p < PIX; ++p) orow[p * OCN] = acc[p];
}

// ---------------------------------------------------------------------------
// Bilinear setup matching the reference exactly.
// ---------------------------------------------------------------------------
__device__ __forceinline__ void bilin_setup(float y, float x,
    int& i00, int& i01, int& i10, int& i11,
    float& w00, float& w01, float& w10, float& w11)
{
    y = fminf(fmaxf(y, 0.f), 199.f);
    x = fminf(fmaxf(x, 0.f), 199.f);
    float y0f = floorf(y), x0f = floorf(x);
    int y0 = (int)y0f, x0i = (int)x0f;
    int y1 = min(y0 + 1, 199), x1 = min(x0i + 1, 199);
    float wy = y - y0f, wx = x - x0f;
    i00 = y0 * Ww + x0i;  i01 = y0 * Ww + x1;
    i10 = y1 * Ww + x0i;  i11 = y1 * Ww + x1;
    w00 = (1.f - wy) * (1.f - wx);
    w01 = (1.f - wy) * wx;
    w10 = wy * (1.f - wx);
    w11 = wy * wx;
}

// ---------------------------------------------------------------------------
// Per-ROI two-stage deformable PS-RoI pooling.
// ---------------------------------------------------------------------------
__global__ __launch_bounds__(256) void psroi_kernel(
    const float* __restrict__ feat, const float* __restrict__ rois,
    const float* __restrict__ om, float* __restrict__ out)
{
    int n = blockIdx.x;
    int t = threadIdx.x;

    float x1 = rois[n * 5 + 1], y1 = rois[n * 5 + 2];
    float x2 = rois[n * 5 + 3], y2 = rois[n * 5 + 4];
    float rw = x2 - x1 + 1.0f, rh = y2 - y1 + 1.0f;
    float fx1 = x1 * 0.0625f, fy1 = y1 * 0.0625f;
    float bw = (rw * 0.0625f) / 7.0f;
    float bh = (rh * 0.0625f) / 7.0f;

    __shared__ float offs[49][2];

    if (t < 49) {
        int bi = t / 7, bj = t % 7;
        float ax = 0.f, ay = 0.f;
#pragma unroll
        for (int ss = 0; ss < 4; ++ss) {
            float sj = ((float)(ss & 1) + 0.5f) * 0.5f;
            float si = ((float)(ss >> 1) + 0.5f) * 0.5f;
            float gx = fx1 + ((float)bj + sj) * bw;
            float gy = fy1 + ((float)bi + si) * bh;
            int i00, i01, i10, i11; float w00, w01, w10, w11;
            bilin_setup(gy, gx, i00, i01, i10, i11, w00, w01, w10, w11);
            int c0 = t * 2;
            const float* p00 = om + (size_t)i00 * OCN + c0;
            const float* p01 = om + (size_t)i01 * OCN + c0;
            const float* p10 = om + (size_t)i10 * OCN + c0;
            const float* p11 = om + (size_t)i11 * OCN + c0;
            ax += w00 * p00[0] + w01 * p01[0] + w10 * p10[0] + w11 * p11[0];
            ay += w00 * p00[1] + w01 * p01[1] + w10 * p10[1] + w11 * p11[1];
        }
        offs[t][0] = ax * 0.25f * rw * 0.1f * 0.0625f;
        offs[t][1] = ay * 0.25f * rh * 0.1f * 0.0625f;
    }
    __syncthreads();

    for (int o = t; o < KK * KK * COUT; o += blockDim.x) {
        int bin = o / COUT, c = o % COUT;
        int bi = bin / 7, bj = bin % 7;
        float dx = offs[bin][0], dy = offs[bin][1];
        int ch = bin * COUT + c;
        float acc = 0.f;
#pragma unroll
        for (int ss = 0; ss < 4; ++ss) {
            float sj = ((float)(ss & 1) + 0.5f) * 0.5f;
            float si = ((float)(ss >> 1) + 0.5f) * 0.5f;
            float gx = fx1 + ((float)bj + sj) * bw + dx;
            float gy = fy1 + ((float)bi + si) * bh + dy;
            int i00, i01, i10, i11; float w00, w01, w10, w11;
            bilin_setup(gy, gx, i00, i01, i10, i11, w00, w01, w10, w11);
            acc += w00 * feat[(size_t)i00 * CIN + ch]
                 + w01 * feat[(size_t)i01 * CIN + ch]
                 + w10 * feat[(size_t)i10 * CIN + ch]
                 + w11 * feat[(size_t)i11 * CIN + ch];
        }
        out[(size_t)n * (KK * KK * COUT) + o] = acc * 0.25f;
    }
}

extern "C" void kernel_launch(void* const* d_in, const int* in_sizes, int n_in,
                              void* d_out, int out_size, void* d_ws, size_t ws_size,
                              hipStream_t stream) {
    const float* feat = (const float*)d_in[0];   // [1,200,200,490]
    const float* rois = (const float*)d_in[1];   // [512,5]
    const float* w    = (const float*)d_in[2];   // [3,3,490,98]
    float* out = (float*)d_out;                  // [512,7,7,10]

    const size_t OM_BYTES = (size_t)NPIX * OCN * 4;                 // 15,680,000
    const size_t BP_BYTES = (size_t)NU32 * NT * 64 * 8 * 2;         // 1,179,648
    const size_t PF_BYTES = (size_t)PH * PW * PC * 2;               // 41,783,296
    const size_t NEEDED = OM_BYTES + BP_BYTES + PF_BYTES;

    if (ws_size >= NEEDED) {
        float* om = (float*)d_ws;
        __hip_bfloat16* bp = (__hip_bfloat16*)((char*)d_ws + OM_BYTES);
        __hip_bfloat16* pf = (__hip_bfloat16*)((char*)d_ws + OM_BYTES + BP_BYTES);

        int wThreads = NU32 * NT * 64 * 8;              // 589,824
        pack_w_kernel<<<(wThreads + 255) / 256, 256, 0, stream>>>(w, bp);
        int fThreads = PH * PW * (PC / 8);              // 2,611,456
        pack_feat_kernel<<<(fThreads + 255) / 256, 256, 0, stream>>>(feat, pf);
        conv_mfma_kernel<<<250, 640, 0, stream>>>(
            (const short*)pf, (const short*)bp, om);
        psroi_kernel<<<NROIS, 256, 0, stream>>>(feat, rois, om, out);
    } else {
        // fallback fp32 path
        float* zero = (float*)d_ws;
        float* om   = (float*)d_ws + 1024;
        hipMemsetAsync(d_ws, 0, 4096, stream);
        int convThreads = Hh * (Ww / PIX) * OCN;
        conv3x3_kernel<<<(convThreads + 255) / 256, 256, 0, stream>>>(feat, w, zero, om);
        psroi_kernel<<<NROIS, 256, 0, stream>>>(feat, rois, om, out);
    }
}

// Round 10
// 133.873 us; speedup vs baseline: 1.0028x; 1.0028x over previous
//
#include <hip/hip_runtime.h>
#include <hip/hip_bf16.h>

#define Hh   200
#define Ww   200
#define CIN  490
#define OCN  98      // 2*K*K
#define KK   7
#define COUT 10
#define NROIS 512
#define PIX  8

#define PH   202     // padded H
#define PW   202     // padded W
#define PC   512     // padded channels
#define NPIX (Hh * Ww)          // 40000
#define NT   4                  // N tiles of 32 (128 cols, 98 real)
#define NU32 288                // 32 kc16 * 9 taps (kc-major: u = kc16*9 + tap)
#define GRU  8                  // units per granule
#define NG32 36                 // 288 / 8
#define RING 16                 // LDS ring slots (2 granules)

typedef __attribute__((ext_vector_type(8))) short short8;
typedef __attribute__((ext_vector_type(4))) float float4v;
typedef __attribute__((ext_vector_type(16))) float float16v;

// ---------------------------------------------------------------------------
// Pack features fp32 [200,200,490] -> bf16 [202,202,512], zero borders+pad.
// ---------------------------------------------------------------------------
__global__ __launch_bounds__(256) void pack_feat_kernel(
    const float* __restrict__ feat, __hip_bfloat16* __restrict__ pf)
{
    int tid = blockIdx.x * 256 + threadIdx.x;
    if (tid >= PH * PW * (PC / 8)) return;
    int c8  = (tid & 63) * 8;
    int pix = tid >> 6;
    int py = pix / PW, px = pix % PW;
    __hip_bfloat16* dst = pf + (size_t)pix * PC + c8;
    bool interior = (py >= 1 && py <= Hh && px >= 1 && px <= Ww);

    __hip_bfloat16 v[8];
    if (interior && c8 + 8 <= CIN) {
        const float* s = feat + ((size_t)(py - 1) * Ww + (px - 1)) * CIN + c8;
#pragma unroll
        for (int q = 0; q < 4; ++q) {
            float2 f2 = *reinterpret_cast<const float2*>(s + q * 2);
            v[q * 2]     = __float2bfloat16(f2.x);
            v[q * 2 + 1] = __float2bfloat16(f2.y);
        }
    } else {
        const float* s = interior ? feat + ((size_t)(py - 1) * Ww + (px - 1)) * CIN : nullptr;
#pragma unroll
        for (int j = 0; j < 8; ++j) {
            float val = (interior && (c8 + j) < CIN) ? s[c8 + j] : 0.f;
            v[j] = __float2bfloat16(val);
        }
    }
    *reinterpret_cast<short8*>(dst) = *reinterpret_cast<short8*>(v);
}

// ---------------------------------------------------------------------------
// Pack weights fp32 [3,3,490,98] -> bf16 in 32x32x16 MFMA B-fragment order,
// kc-major: bp[u][t][lane][j], u = kc16*9 + tap, with
// k = kc16*16 + (lane>>5)*8 + j, n = t*32 + (lane&31);
// zero-padded for k>=490 or n>=98.
// ---------------------------------------------------------------------------
__global__ __launch_bounds__(256) void pack_w_kernel(
    const float* __restrict__ w, __hip_bfloat16* __restrict__ bp)
{
    int idx = blockIdx.x * 256 + threadIdx.x;
    if (idx >= NU32 * NT * 64 * 8) return;
    int j = idx & 7;
    int l = (idx >> 3) & 63;
    int t = (idx >> 9) & 3;
    int u = idx >> 11;               // 0..287, u = kc16*9 + tap
    int kc = u / 9, tap = u % 9;
    int k = kc * 16 + ((l >> 5) * 8) + j;
    int n = t * 32 + (l & 31);
    float val = (k < CIN && n < OCN) ? w[((size_t)tap * CIN + k) * OCN + n] : 0.f;
    bp[idx] = __float2bfloat16(val);
}

// ---------------------------------------------------------------------------
// Implicit-GEMM 3x3 conv via 32x32x16 MFMA with LDS-shared B.
// Block = 640 threads (10 waves) = 5 mpos x 2 nh; block M = 160; grid = 250.
// Wave = M=32 x N=64 (2 of 4 N-tiles).
// Granule = 8 kc16-units (36 iterations — r7's proven cadence: the compute
// window per iteration (~2000 cyc) covers global-load latency; r9's 72
// tiny iterations were latency-bound). Ring = 16 slots x 4 KB = 64 KB LDS,
// double-buffered per granule. Per-CU LDS reads = 57% of r7's.
// B reg-staged issue-early/write-late; A prefetched one granule ahead.
// ---------------------------------------------------------------------------
__global__ __launch_bounds__(640) void conv_mfma_kernel(
    const short* __restrict__ pf,   // padfeat bf16 [202*202*512]
    const short* __restrict__ bp,   // bpack bf16 [288*4*64*8]
    float* __restrict__ om)         // [40000,98]
{
    __shared__ short bsm[RING * 2048];  // 16 unit-slots x 4096 B = 65,536 B

    int l = threadIdx.x & 63;
    int w = threadIdx.x >> 6;        // wave 0..9
    int nh = w & 1;                  // N-half: tiles {0,1} or {2,3}
    int m0 = blockIdx.x * 160 + (w >> 1) * 32;

    int row = m0 + (l & 31);
    int y = row / Ww, x = row % Ww;
    const short* abase = pf + ((size_t)(y * PW + x) * PC) + ((l >> 5) * 8);

    float16v acc0 = {0.f,0.f,0.f,0.f,0.f,0.f,0.f,0.f,0.f,0.f,0.f,0.f,0.f,0.f,0.f,0.f};
    float16v acc1 = {0.f,0.f,0.f,0.f,0.f,0.f,0.f,0.f,0.f,0.f,0.f,0.f,0.f,0.f,0.f,0.f};

    // A offset (in shorts) for k-unit u = kc16*9 + tap
    auto aOff = [&](int u) -> int {
        int kc = u / 9, tap = u - kc * 9;
        int ky = tap / 3, kx = tap - ky * 3;
        return (ky * PW + kx) * PC + kc * 16;
    };

    // ---- prologue: stage granule 0 (units 0..7 x 4 tiles = 32 slot-writes) --
#pragma unroll
    for (int s = 0; s < 4; ++s) {
        int i = w + s * 10;
        if (i < 32) {
            int uu = i >> 2, t = i & 3;
            short8 v = *reinterpret_cast<const short8*>(
                bp + ((size_t)(uu * NT + t)) * 512 + l * 8);
            *reinterpret_cast<short8*>(&bsm[(uu & (RING-1)) * 2048 + t * 512 + l * 8]) = v;
        }
    }
    // prefetch A for granule 0
    short8 a0 = *reinterpret_cast<const short8*>(abase + aOff(0));
    short8 a1 = *reinterpret_cast<const short8*>(abase + aOff(1));
    short8 a2 = *reinterpret_cast<const short8*>(abase + aOff(2));
    short8 a3 = *reinterpret_cast<const short8*>(abase + aOff(3));
    short8 a4 = *reinterpret_cast<const short8*>(abase + aOff(4));
    short8 a5 = *reinterpret_cast<const short8*>(abase + aOff(5));
    short8 a6 = *reinterpret_cast<const short8*>(abase + aOff(6));
    short8 a7 = *reinterpret_cast<const short8*>(abase + aOff(7));
    __syncthreads();

    for (int g = 0; g < NG32; ++g) {
        bool more = (g < NG32 - 1);
        int u0n = (g + 1) * GRU;

        // 1) issue B global loads for granule g+1 (regs, named slots)
        short8 st0, st1, st2, st3;
        int off0 = -1, off1 = -1, off2 = -1, off3 = -1;
        if (more) {
#define STAGE_LOAD(S, STV, OFFV)                                               \
            {                                                                  \
                int i = w + (S) * 10;                                          \
                if (i < 32) {                                                  \
                    int uu = u0n + (i >> 2), t = i & 3;                        \
                    STV = *reinterpret_cast<const short8*>(                    \
                        bp + ((size_t)(uu * NT + t)) * 512 + l * 8);           \
                    OFFV = (uu & (RING-1)) * 2048 + t * 512 + l * 8;           \
                }                                                              \
            }
            STAGE_LOAD(0, st0, off0)
            STAGE_LOAD(1, st1, off1)
            STAGE_LOAD(2, st2, off2)
            STAGE_LOAD(3, st3, off3)
#undef STAGE_LOAD
        }
        // 2) issue A loads for granule g+1
        short8 n0, n1, n2, n3, n4, n5, n6, n7;
        if (more) {
            n0 = *reinterpret_cast<const short8*>(abase + aOff(u0n + 0));
            n1 = *reinterpret_cast<const short8*>(abase + aOff(u0n + 1));
            n2 = *reinterpret_cast<const short8*>(abase + aOff(u0n + 2));
            n3 = *reinterpret_cast<const short8*>(abase + aOff(u0n + 3));
            n4 = *reinterpret_cast<const short8*>(abase + aOff(u0n + 4));
            n5 = *reinterpret_cast<const short8*>(abase + aOff(u0n + 5));
            n6 = *reinterpret_cast<const short8*>(abase + aOff(u0n + 6));
            n7 = *reinterpret_cast<const short8*>(abase + aOff(u0n + 7));
        }

        // 3) compute granule g: 8 units x 2 tiles (this wave's N-half)
        int u0 = g * GRU;
#define COMPUTE_UNIT(J, AREG)                                                   \
        {                                                                       \
            int sbase = ((u0 + J) & (RING-1)) * 2048 + nh * 1024 + l * 8;       \
            short8 b0 = *reinterpret_cast<short8*>(&bsm[sbase]);                \
            short8 b1 = *reinterpret_cast<short8*>(&bsm[sbase + 512]);          \
            acc0 = __builtin_amdgcn_mfma_f32_32x32x16_bf16(AREG, b0, acc0, 0, 0, 0); \
            acc1 = __builtin_amdgcn_mfma_f32_32x32x16_bf16(AREG, b1, acc1, 0, 0, 0); \
        }
        COMPUTE_UNIT(0, a0)
        COMPUTE_UNIT(1, a1)
        COMPUTE_UNIT(2, a2)
        COMPUTE_UNIT(3, a3)
        COMPUTE_UNIT(4, a4)
        COMPUTE_UNIT(5, a5)
        COMPUTE_UNIT(6, a6)
        COMPUTE_UNIT(7, a7)
#undef COMPUTE_UNIT

        // 4) write staged B to LDS
        if (off0 >= 0) *reinterpret_cast<short8*>(&bsm[off0]) = st0;
        if (off1 >= 0) *reinterpret_cast<short8*>(&bsm[off1]) = st1;
        if (off2 >= 0) *reinterpret_cast<short8*>(&bsm[off2]) = st2;
        if (off3 >= 0) *reinterpret_cast<short8*>(&bsm[off3]) = st3;
        // 5) rotate A prefetch
        if (more) {
            a0 = n0; a1 = n1; a2 = n2; a3 = n3;
            a4 = n4; a5 = n5; a6 = n6; a7 = n7;
        }
        __syncthreads();
    }

    // epilogue: store C. D layout: col=lane&31, row=(reg&3)+8*(reg>>2)+4*(lane>>5)
    int col_lo = l & 31;
    int rbase = m0 + 4 * (l >> 5);
#pragma unroll
    for (int tt = 0; tt < 2; ++tt) {
        int col = (nh * 2 + tt) * 32 + col_lo;
        if (col < OCN) {
            const float16v& A = tt ? acc1 : acc0;
#pragma unroll
            for (int reg = 0; reg < 16; ++reg) {
                int r = rbase + (reg & 3) + 8 * (reg >> 2);
                om[(size_t)r * OCN + col] = A[reg];
            }
        }
    }
}

// ---------------------------------------------------------------------------
// Fallback fp32 conv (used only if ws too small for the MFMA path).
// ---------------------------------------------------------------------------
__global__ __launch_bounds__(256) void conv3x3_kernel(
    const float* __restrict__ feat, const float* __restrict__ w,
    const float* __restrict__ zero, float* __restrict__ om)
{
    int idx = blockIdx.x * blockDim.x + threadIdx.x;
    if (idx >= Hh * (Ww / PIX) * OCN) return;
    int oc = idx % OCN;
    int g  = idx / OCN;
    int x0 = (g % (Ww / PIX)) * PIX;
    int y  = g / (Ww / PIX);

    float acc[PIX];
#pragma unroll
    for (int p = 0; p < PIX; ++p) acc[p] = 0.f;

    for (int ky = 0; ky < 3; ++ky) {
        int yy = y + ky - 1;
        if (yy < 0 || yy >= Hh) continue;
        const float* frow = feat + (size_t)yy * Ww * CIN;
        for (int kx = 0; kx < 3; ++kx) {
            const float* wp = w + ((ky * 3 + kx) * CIN) * OCN + oc;
            const float* fp[PIX];
#pragma unroll
            for (int p = 0; p < PIX; ++p) {
                int xx = x0 + p + kx - 1;
                fp[p] = (xx >= 0 && xx < Ww) ? (frow + (size_t)xx * CIN) : zero;
            }
            for (int ic = 0; ic < CIN; ic += 2) {
                float w0 = wp[ic * OCN];
                float w1 = wp[(ic + 1) * OCN];
#pragma unroll
                for (int p = 0; p < PIX; ++p) {
                    float2 f = *reinterpret_cast<const float2*>(fp[p] + ic);
                    acc[p] = fmaf(f.x, w0, acc[p]);
                    acc[p] = fmaf(f.y, w1, acc[p]);
                }
            }
        }
    }
    float* orow = om + ((size_t)y * Ww + x0) * OCN + oc;
#pragma unroll
    for (int p = 0; p < PIX; ++p) orow[p * OCN] = acc[p];
}

// ---------------------------------------------------------------------------
// Bilinear setup matching the reference exactly.
// ---------------------------------------------------------------------------
__device__ __forceinline__ void bilin_setup(float y, float x,
    int& i00, int& i01, int& i10, int& i11,
    float& w00, float& w01, float& w10, float& w11)
{
    y = fminf(fmaxf(y, 0.f), 199.f);
    x = fminf(fmaxf(x, 0.f), 199.f);
    float y0f = floorf(y), x0f = floorf(x);
    int y0 = (int)y0f, x0i = (int)x0f;
    int y1 = min(y0 + 1, 199), x1 = min(x0i + 1, 199);
    float wy = y - y0f, wx = x - x0f;
    i00 = y0 * Ww + x0i;  i01 = y0 * Ww + x1;
    i10 = y1 * Ww + x0i;  i11 = y1 * Ww + x1;
    w00 = (1.f - wy) * (1.f - wx);
    w01 = (1.f - wy) * wx;
    w10 = wy * (1.f - wx);
    w11 = wy * wx;
}

// ---------------------------------------------------------------------------
// Per-ROI two-stage deformable PS-RoI pooling.
// ---------------------------------------------------------------------------
__global__ __launch_bounds__(256) void psroi_kernel(
    const float* __restrict__ feat, const float* __restrict__ rois,
    const float* __restrict__ om, float* __restrict__ out)
{
    int n = blockIdx.x;
    int t = threadIdx.x;

    float x1 = rois[n * 5 + 1], y1 = rois[n * 5 + 2];
    float x2 = rois[n * 5 + 3], y2 = rois[n * 5 + 4];
    float rw = x2 - x1 + 1.0f, rh = y2 - y1 + 1.0f;
    float fx1 = x1 * 0.0625f, fy1 = y1 * 0.0625f;
    float bw = (rw * 0.0625f) / 7.0f;
    float bh = (rh * 0.0625f) / 7.0f;

    __shared__ float offs[49][2];

    if (t < 49) {
        int bi = t / 7, bj = t % 7;
        float ax = 0.f, ay = 0.f;
#pragma unroll
        for (int ss = 0; ss < 4; ++ss) {
            float sj = ((float)(ss & 1) + 0.5f) * 0.5f;
            float si = ((float)(ss >> 1) + 0.5f) * 0.5f;
            float gx = fx1 + ((float)bj + sj) * bw;
            float gy = fy1 + ((float)bi + si) * bh;
            int i00, i01, i10, i11; float w00, w01, w10, w11;
            bilin_setup(gy, gx, i00, i01, i10, i11, w00, w01, w10, w11);
            int c0 = t * 2;
            const float* p00 = om + (size_t)i00 * OCN + c0;
            const float* p01 = om + (size_t)i01 * OCN + c0;
            const float* p10 = om + (size_t)i10 * OCN + c0;
            const float* p11 = om + (size_t)i11 * OCN + c0;
            ax += w00 * p00[0] + w01 * p01[0] + w10 * p10[0] + w11 * p11[0];
            ay += w00 * p00[1] + w01 * p01[1] + w10 * p10[1] + w11 * p11[1];
        }
        offs[t][0] = ax * 0.25f * rw * 0.1f * 0.0625f;
        offs[t][1] = ay * 0.25f * rh * 0.1f * 0.0625f;
    }
    __syncthreads();

    for (int o = t; o < KK * KK * COUT; o += blockDim.x) {
        int bin = o / COUT, c = o % COUT;
        int bi = bin / 7, bj = bin % 7;
        float dx = offs[bin][0], dy = offs[bin][1];
        int ch = bin * COUT + c;
        float acc = 0.f;
#pragma unroll
        for (int ss = 0; ss < 4; ++ss) {
            float sj = ((float)(ss & 1) + 0.5f) * 0.5f;
            float si = ((float)(ss >> 1) + 0.5f) * 0.5f;
            float gx = fx1 + ((float)bj + sj) * bw + dx;
            float gy = fy1 + ((float)bi + si) * bh + dy;
            int i00, i01, i10, i11; float w00, w01, w10, w11;
            bilin_setup(gy, gx, i00, i01, i10, i11, w00, w01, w10, w11);
            acc += w00 * feat[(size_t)i00 * CIN + ch]
                 + w01 * feat[(size_t)i01 * CIN + ch]
                 + w10 * feat[(size_t)i10 * CIN + ch]
                 + w11 * feat[(size_t)i11 * CIN + ch];
        }
        out[(size_t)n * (KK * KK * COUT) + o] = acc * 0.25f;
    }
}

extern "C" void kernel_launch(void* const* d_in, const int* in_sizes, int n_in,
                              void* d_out, int out_size, void* d_ws, size_t ws_size,
                              hipStream_t stream) {
    const float* feat = (const float*)d_in[0];   // [1,200,200,490]
    const float* rois = (const float*)d_in[1];   // [512,5]
    const float* w    = (const float*)d_in[2];   // [3,3,490,98]
    float* out = (float*)d_out;                  // [512,7,7,10]

    const size_t OM_BYTES = (size_t)NPIX * OCN * 4;                 // 15,680,000
    const size_t BP_BYTES = (size_t)NU32 * NT * 64 * 8 * 2;         // 1,179,648
    const size_t PF_BYTES = (size_t)PH * PW * PC * 2;               // 41,783,296
    const size_t NEEDED = OM_BYTES + BP_BYTES + PF_BYTES;

    if (ws_size >= NEEDED) {
        float* om = (float*)d_ws;
        __hip_bfloat16* bp = (__hip_bfloat16*)((char*)d_ws + OM_BYTES);
        __hip_bfloat16* pf = (__hip_bfloat16*)((char*)d_ws + OM_BYTES + BP_BYTES);

        int wThreads = NU32 * NT * 64 * 8;              // 589,824
        pack_w_kernel<<<(wThreads + 255) / 256, 256, 0, stream>>>(w, bp);
        int fThreads = PH * PW * (PC / 8);              // 2,611,456
        pack_feat_kernel<<<(fThreads + 255) / 256, 256, 0, stream>>>(feat, pf);
        conv_mfma_kernel<<<250, 640, 0, stream>>>(
            (const short*)pf, (const short*)bp, om);
        psroi_kernel<<<NROIS, 256, 0, stream>>>(feat, rois, om, out);
    } else {
        // fallback fp32 path
        float* zero = (float*)d_ws;
        float* om   = (float*)d_ws + 1024;
        hipMemsetAsync(d_ws, 0, 4096, stream);
        int convThreads = Hh * (Ww / PIX) * OCN;
        conv3x3_kernel<<<(convThreads + 255) / 256, 256, 0, stream>>>(feat, w, zero, om);
        psroi_kernel<<<NROIS, 256, 0, stream>>>(feat, rois, om, out);
    }
}

// Round 11
// 97.212 us; speedup vs baseline: 1.3810x; 1.3771x over previous
//
#include <hip/hip_runtime.h>
#include <hip/hip_bf16.h>

#define Hh   200
#define Ww   200
#define CIN  490
#define OCN  98      // 2*K*K
#define KK   7
#define COUT 10
#define NROIS 512
#define PIX  8

#define PH   202     // padded H
#define PW   202     // padded W
#define PC   512     // padded channels
#define NPIX (Hh * Ww)          // 40000
#define KCN  16                 // k-chunks of 32 per tap (512/32)
#define NF   7                  // N fragments (112 cols)
#define NUNITS 144              // 16 kc * 9 taps (kc-major: u = kc*9 + tap)
#define HGRAN  18               // granules per k-half (72 units / 4)
#define HALF_SHORTS (8 * 3584)  // LDS shorts per k-half (57,344 B)

typedef __attribute__((ext_vector_type(8))) short short8;
typedef __attribute__((ext_vector_type(4))) float float4v;

// ---------------------------------------------------------------------------
// Pack features fp32 [200,200,490] -> bf16 [202,202,512], zero borders+pad.
// ---------------------------------------------------------------------------
__global__ __launch_bounds__(256) void pack_feat_kernel(
    const float* __restrict__ feat, __hip_bfloat16* __restrict__ pf)
{
    int tid = blockIdx.x * 256 + threadIdx.x;
    if (tid >= PH * PW * (PC / 8)) return;
    int c8  = (tid & 63) * 8;
    int pix = tid >> 6;
    int py = pix / PW, px = pix % PW;
    __hip_bfloat16* dst = pf + (size_t)pix * PC + c8;
    bool interior = (py >= 1 && py <= Hh && px >= 1 && px <= Ww);

    __hip_bfloat16 v[8];
    if (interior && c8 + 8 <= CIN) {
        const float* s = feat + ((size_t)(py - 1) * Ww + (px - 1)) * CIN + c8;
#pragma unroll
        for (int q = 0; q < 4; ++q) {
            float2 f2 = *reinterpret_cast<const float2*>(s + q * 2);
            v[q * 2]     = __float2bfloat16(f2.x);
            v[q * 2 + 1] = __float2bfloat16(f2.y);
        }
    } else {
        const float* s = interior ? feat + ((size_t)(py - 1) * Ww + (px - 1)) * CIN : nullptr;
#pragma unroll
        for (int j = 0; j < 8; ++j) {
            float val = (interior && (c8 + j) < CIN) ? s[c8 + j] : 0.f;
            v[j] = __float2bfloat16(val);
        }
    }
    *reinterpret_cast<short8*>(dst) = *reinterpret_cast<short8*>(v);
}

// ---------------------------------------------------------------------------
// Pack weights fp32 [3,3,490,98] -> bf16 in MFMA B-fragment order, kc-major:
// bpack[u][f][lane][j], u = kc*9 + tap, with k = kc*32 + (lane>>4)*8 + j,
// n = f*16 + (lane&15); zero-padded for k>=490 or n>=98.
// ---------------------------------------------------------------------------
__global__ __launch_bounds__(256) void pack_w_kernel(
    const float* __restrict__ w, __hip_bfloat16* __restrict__ bp)
{
    int idx = blockIdx.x * 256 + threadIdx.x;
    if (idx >= NUNITS * NF * 64 * 8) return;
    int j = idx & 7;
    int l = (idx >> 3) & 63;
    int f = (idx >> 9) % NF;
    int u = idx / (NF * 512);        // kc*9 + tap
    int kc = u / 9, tap = u % 9;
    int k = kc * 32 + ((l >> 4) * 8) + j;
    int n = f * 16 + (l & 15);
    float val = (k < CIN && n < OCN) ? w[((size_t)tap * CIN + k) * OCN + n] : 0.f;
    bp[idx] = __float2bfloat16(val);
}

// ---------------------------------------------------------------------------
// Implicit-GEMM 3x3 conv via MFMA, LDS-shared B, K-SPLIT waves (r8 structure
// with the spill fixed). Block = 640 threads (10 waves); grid = 250.
// Wave (mpos, ks): mpos owns M rows [mpos*32, +32) (MR=2); ks owns k-units
// [ks*72, +72) (18 granules of 4). Each B ds_read feeds 2 MFMAs -> LDS-read
// bytes HALF of r7 at same occupancy and perfect balance.
// Spill fix vs r8: __launch_bounds__(640,2) raises the VGPR cap, and A regs
// are reloaded in-place after last use (no second prefetch copy): live set
// ~130 VGPR. Each half double-buffers B in its own 57,344 B region.
// Epilogue: ks=1 partial accs -> LDS -> ks=0 adds and stores.
// ---------------------------------------------------------------------------
__global__ __launch_bounds__(640, 2) void conv_mfma_kernel(
    const short* __restrict__ pf,   // padfeat bf16 [202*202*512]
    const short* __restrict__ bp,   // bpack bf16 [144*7*64*8]
    float* __restrict__ om)         // [40000,98]
{
    __shared__ short bsm[2 * HALF_SHORTS];  // 114,688 B

    // bijective XCD chunked swizzle: nwg=250, q=31, r=2
    int orig = blockIdx.x;
    int xcd = orig & 7;
    int pos = orig >> 3;
    int blk = ((xcd < 2) ? xcd * 32 : 64 + (xcd - 2) * 31) + pos;

    int l = threadIdx.x & 63;
    int w = threadIdx.x >> 6;        // wave 0..9
    int mpos = w % 5;                // 0..4
    int ks = w / 5;                  // 0..1 (k-half)
    int ubase = ks * 72;             // first unit of this half
    int m0 = blk * 160 + mpos * 32;

    // A base pointers for the 2 M-frags
    const short* abase0;
    const short* abase1;
    {
        int row0 = m0 + (l & 15);
        int row1 = m0 + 16 + (l & 15);
        int y0 = row0 / Ww, x0 = row0 % Ww;
        int y1 = row1 / Ww, x1 = row1 % Ww;
        abase0 = pf + ((size_t)(y0 * PW + x0) * PC) + ((l >> 4) * 8);
        abase1 = pf + ((size_t)(y1 * PW + x1) * PC) + ((l >> 4) * 8);
    }

    float4v acc[2][NF];
#pragma unroll
    for (int r = 0; r < 2; ++r)
#pragma unroll
        for (int f = 0; f < NF; ++f) acc[r][f] = (float4v){0.f, 0.f, 0.f, 0.f};

    // A offset (in shorts) for k-unit u = kc*9 + tap
    auto aOff = [&](int u) -> int {
        int kc = u / 9, tap = u - kc * 9;
        int ky = tap / 3, kx = tap - ky * 3;
        return (ky * PW + kx) * PC + kc * 32;
    };
    int lbase = ks * HALF_SHORTS;    // this half's LDS base (shorts)

    // ---- prologue: stage own half's granule 0 (28 slot-writes, 5 waves) ----
#pragma unroll
    for (int s = 0; s < 6; ++s) {
        int i = mpos + s * 5;
        if (i < 28) {
            int uu = ubase + i / 7, f = i % 7;
            short8 v = *reinterpret_cast<const short8*>(
                bp + ((size_t)(uu * NF + f)) * 512 + l * 8);
            *reinterpret_cast<short8*>(
                &bsm[lbase + (uu & 7) * 3584 + f * 512 + l * 8]) = v;
        }
    }
    // prefetch A for granule 0 (8 short8 registers, reused in-place)
    short8 a00 = *reinterpret_cast<const short8*>(abase0 + aOff(ubase + 0));
    short8 a01 = *reinterpret_cast<const short8*>(abase0 + aOff(ubase + 1));
    short8 a02 = *reinterpret_cast<const short8*>(abase0 + aOff(ubase + 2));
    short8 a03 = *reinterpret_cast<const short8*>(abase0 + aOff(ubase + 3));
    short8 a10 = *reinterpret_cast<const short8*>(abase1 + aOff(ubase + 0));
    short8 a11 = *reinterpret_cast<const short8*>(abase1 + aOff(ubase + 1));
    short8 a12 = *reinterpret_cast<const short8*>(abase1 + aOff(ubase + 2));
    short8 a13 = *reinterpret_cast<const short8*>(abase1 + aOff(ubase + 3));
    __syncthreads();

    for (int g = 0; g < HGRAN; ++g) {
        bool more = (g < HGRAN - 1);
        int u0n = ubase + (g + 1) * 4;

        // 1) issue B global loads for own half's granule g+1 (6 reg slots)
        short8 st0, st1, st2, st3, st4, st5;
        int off0 = -1, off1 = -1, off2 = -1, off3 = -1, off4 = -1, off5 = -1;
        if (more) {
#define STAGE_LOAD(S, STV, OFFV)                                               \
            {                                                                  \
                int i = mpos + (S) * 5;                                        \
                if (i < 28) {                                                  \
                    int uu = u0n + i / 7, f = i % 7;                           \
                    STV = *reinterpret_cast<const short8*>(                    \
                        bp + ((size_t)(uu * NF + f)) * 512 + l * 8);           \
                    OFFV = lbase + (uu & 7) * 3584 + f * 512 + l * 8;          \
                }                                                              \
            }
            STAGE_LOAD(0, st0, off0)
            STAGE_LOAD(1, st1, off1)
            STAGE_LOAD(2, st2, off2)
            STAGE_LOAD(3, st3, off3)
            STAGE_LOAD(4, st4, off4)
            STAGE_LOAD(5, st5, off5)
#undef STAGE_LOAD
        }

        // 2) compute granule g; reload each A reg IN-PLACE after its last use
        int u0 = ubase + g * 4;
#define UNIT_STEP(J, AR0, AR1)                                                  \
        {                                                                       \
            int sbase = lbase + ((u0 + J) & 7) * 3584 + l * 8;                  \
            _Pragma("unroll")                                                   \
            for (int f = 0; f < NF; ++f) {                                      \
                short8 b = *reinterpret_cast<short8*>(&bsm[sbase + f * 512]);   \
                acc[0][f] = __builtin_amdgcn_mfma_f32_16x16x32_bf16(            \
                    AR0, b, acc[0][f], 0, 0, 0);                                \
                acc[1][f] = __builtin_amdgcn_mfma_f32_16x16x32_bf16(            \
                    AR1, b, acc[1][f], 0, 0, 0);                                \
            }                                                                   \
            if (more) {                                                         \
                AR0 = *reinterpret_cast<const short8*>(abase0 + aOff(u0n + J)); \
                AR1 = *reinterpret_cast<const short8*>(abase1 + aOff(u0n + J)); \
            }                                                                   \
        }
        UNIT_STEP(0, a00, a10)
        UNIT_STEP(1, a01, a11)
        UNIT_STEP(2, a02, a12)
        UNIT_STEP(3, a03, a13)
#undef UNIT_STEP

        // 3) write staged B to LDS
        if (off0 >= 0) *reinterpret_cast<short8*>(&bsm[off0]) = st0;
        if (off1 >= 0) *reinterpret_cast<short8*>(&bsm[off1]) = st1;
        if (off2 >= 0) *reinterpret_cast<short8*>(&bsm[off2]) = st2;
        if (off3 >= 0) *reinterpret_cast<short8*>(&bsm[off3]) = st3;
        if (off4 >= 0) *reinterpret_cast<short8*>(&bsm[off4]) = st4;
        if (off5 >= 0) *reinterpret_cast<short8*>(&bsm[off5]) = st5;
        __syncthreads();
    }

    // ---- epilogue: reduce the two k-halves, then store ----
    // lred[mpos][r][f]: one float4 per lane -> 5*2*7*64*4 floats = 71,680 B
    float* lred = (float*)bsm;
    if (ks == 1) {
#pragma unroll
        for (int r = 0; r < 2; ++r)
#pragma unroll
            for (int f = 0; f < NF; ++f) {
                int idx = (((mpos * 2 + r) * NF + f) * 64 + l) * 4;
                *reinterpret_cast<float4v*>(&lred[idx]) = acc[r][f];
            }
    }
    __syncthreads();
    if (ks == 0) {
        int n = l & 15;
#pragma unroll
        for (int r = 0; r < 2; ++r) {
            int rbase = m0 + r * 16 + ((l >> 4) * 4);
#pragma unroll
            for (int f = 0; f < NF; ++f) {
                int idx = (((mpos * 2 + r) * NF + f) * 64 + l) * 4;
                float4v other = *reinterpret_cast<float4v*>(&lred[idx]);
                float4v tot = acc[r][f] + other;
                int col = f * 16 + n;
                if (col < OCN) {
#pragma unroll
                    for (int j = 0; j < 4; ++j)
                        om[(size_t)(rbase + j) * OCN + col] = tot[j];
                }
            }
        }
    }
}

// ---------------------------------------------------------------------------
// Fallback fp32 conv (used only if ws too small for the MFMA path).
// ---------------------------------------------------------------------------
__global__ __launch_bounds__(256) void conv3x3_kernel(
    const float* __restrict__ feat, const float* __restrict__ w,
    const float* __restrict__ zero, float* __restrict__ om)
{
    int idx = blockIdx.x * blockDim.x + threadIdx.x;
    if (idx >= Hh * (Ww / PIX) * OCN) return;
    int oc = idx % OCN;
    int g  = idx / OCN;
    int x0 = (g % (Ww / PIX)) * PIX;
    int y  = g / (Ww / PIX);

    float acc[PIX];
#pragma unroll
    for (int p = 0; p < PIX; ++p) acc[p] = 0.f;

    for (int ky = 0; ky < 3; ++ky) {
        int yy = y + ky - 1;
        if (yy < 0 || yy >= Hh) continue;
        const float* frow = feat + (size_t)yy * Ww * CIN;
        for (int kx = 0; kx < 3; ++kx) {
            const float* wp = w + ((ky * 3 + kx) * CIN) * OCN + oc;
            const float* fp[PIX];
#pragma unroll
            for (int p = 0; p < PIX; ++p) {
                int xx = x0 + p + kx - 1;
                fp[p] = (xx >= 0 && xx < Ww) ? (frow + (size_t)xx * CIN) : zero;
            }
            for (int ic = 0; ic < CIN; ic += 2) {
                float w0 = wp[ic * OCN];
                float w1 = wp[(ic + 1) * OCN];
#pragma unroll
                for (int p = 0; p < PIX; ++p) {
                    float2 f = *reinterpret_cast<const float2*>(fp[p] + ic);
                    acc[p] = fmaf(f.x, w0, acc[p]);
                    acc[p] = fmaf(f.y, w1, acc[p]);
                }
            }
        }
    }
    float* orow = om + ((size_t)y * Ww + x0) * OCN + oc;
#pragma unroll
    for (int p = 0; p < PIX; ++p) orow[p * OCN] = acc[p];
}

// ---------------------------------------------------------------------------
// Bilinear setup matching the reference exactly.
// ---------------------------------------------------------------------------
__device__ __forceinline__ void bilin_setup(float y, float x,
    int& i00, int& i01, int& i10, int& i11,
    float& w00, float& w01, float& w10, float& w11)
{
    y = fminf(fmaxf(y, 0.f), 199.f);
    x = fminf(fmaxf(x, 0.f), 199.f);
    float y0f = floorf(y), x0f = floorf(x);
    int y0 = (int)y0f, x0i = (int)x0f;
    int y1 = min(y0 + 1, 199), x1 = min(x0i + 1, 199);
    float wy = y - y0f, wx = x - x0f;
    i00 = y0 * Ww + x0i;  i01 = y0 * Ww + x1;
    i10 = y1 * Ww + x0i;  i11 = y1 * Ww + x1;
    w00 = (1.f - wy) * (1.f - wx);
    w01 = (1.f - wy) * wx;
    w10 = wy * (1.f - wx);
    w11 = wy * wx;
}

// ---------------------------------------------------------------------------
// Per-ROI two-stage deformable PS-RoI pooling.
// ---------------------------------------------------------------------------
__global__ __launch_bounds__(256) void psroi_kernel(
    const float* __restrict__ feat, const float* __restrict__ rois,
    const float* __restrict__ om, float* __restrict__ out)
{
    int n = blockIdx.x;
    int t = threadIdx.x;

    float x1 = rois[n * 5 + 1], y1 = rois[n * 5 + 2];
    float x2 = rois[n * 5 + 3], y2 = rois[n * 5 + 4];
    float rw = x2 - x1 + 1.0f, rh = y2 - y1 + 1.0f;
    float fx1 = x1 * 0.0625f, fy1 = y1 * 0.0625f;
    float bw = (rw * 0.0625f) / 7.0f;
    float bh = (rh * 0.0625f) / 7.0f;

    __shared__ float offs[49][2];

    if (t < 49) {
        int bi = t / 7, bj = t % 7;
        float ax = 0.f, ay = 0.f;
#pragma unroll
        for (int ss = 0; ss < 4; ++ss) {
            float sj = ((float)(ss & 1) + 0.5f) * 0.5f;
            float si = ((float)(ss >> 1) + 0.5f) * 0.5f;
            float gx = fx1 + ((float)bj + sj) * bw;
            float gy = fy1 + ((float)bi + si) * bh;
            int i00, i01, i10, i11; float w00, w01, w10, w11;
            bilin_setup(gy, gx, i00, i01, i10, i11, w00, w01, w10, w11);
            int c0 = t * 2;
            const float* p00 = om + (size_t)i00 * OCN + c0;
            const float* p01 = om + (size_t)i01 * OCN + c0;
            const float* p10 = om + (size_t)i10 * OCN + c0;
            const float* p11 = om + (size_t)i11 * OCN + c0;
            ax += w00 * p00[0] + w01 * p01[0] + w10 * p10[0] + w11 * p11[0];
            ay += w00 * p00[1] + w01 * p01[1] + w10 * p10[1] + w11 * p11[1];
        }
        offs[t][0] = ax * 0.25f * rw * 0.1f * 0.0625f;
        offs[t][1] = ay * 0.25f * rh * 0.1f * 0.0625f;
    }
    __syncthreads();

    for (int o = t; o < KK * KK * COUT; o += blockDim.x) {
        int bin = o / COUT, c = o % COUT;
        int bi = bin / 7, bj = bin % 7;
        float dx = offs[bin][0], dy = offs[bin][1];
        int ch = bin * COUT + c;
        float acc = 0.f;
#pragma unroll
        for (int ss = 0; ss < 4; ++ss) {
            float sj = ((float)(ss & 1) + 0.5f) * 0.5f;
            float si = ((float)(ss >> 1) + 0.5f) * 0.5f;
            float gx = fx1 + ((float)bj + sj) * bw + dx;
            float gy = fy1 + ((float)bi + si) * bh + dy;
            int i00, i01, i10, i11; float w00, w01, w10, w11;
            bilin_setup(gy, gx, i00, i01, i10, i11, w00, w01, w10, w11);
            acc += w00 * feat[(size_t)i00 * CIN + ch]
                 + w01 * feat[(size_t)i01 * CIN + ch]
                 + w10 * feat[(size_t)i10 * CIN + ch]
                 + w11 * feat[(size_t)i11 * CIN + ch];
        }
        out[(size_t)n * (KK * KK * COUT) + o] = acc * 0.25f;
    }
}

extern "C" void kernel_launch(void* const* d_in, const int* in_sizes, int n_in,
                              void* d_out, int out_size, void* d_ws, size_t ws_size,
                              hipStream_t stream) {
    const float* feat = (const float*)d_in[0];   // [1,200,200,490]
    const float* rois = (const float*)d_in[1];   // [512,5]
    const float* w    = (const float*)d_in[2];   // [3,3,490,98]
    float* out = (float*)d_out;                  // [512,7,7,10]

    const size_t OM_BYTES = (size_t)NPIX * OCN * 4;                 // 15,680,000
    const size_t BP_BYTES = (size_t)NUNITS * NF * 64 * 8 * 2;       // 1,032,192
    const size_t PF_BYTES = (size_t)PH * PW * PC * 2;               // 41,783,296
    const size_t NEEDED = OM_BYTES + BP_BYTES + PF_BYTES;

    if (ws_size >= NEEDED) {
        float* om = (float*)d_ws;
        __hip_bfloat16* bp = (__hip_bfloat16*)((char*)d_ws + OM_BYTES);
        __hip_bfloat16* pf = (__hip_bfloat16*)((char*)d_ws + OM_BYTES + BP_BYTES);

        int wThreads = NUNITS * NF * 64 * 8;            // 516,096
        pack_w_kernel<<<(wThreads + 255) / 256, 256, 0, stream>>>(w, bp);
        int fThreads = PH * PW * (PC / 8);              // 2,611,456
        pack_feat_kernel<<<(fThreads + 255) / 256, 256, 0, stream>>>(feat, pf);
        conv_mfma_kernel<<<250, 640, 0, stream>>>(
            (const short*)pf, (const short*)bp, om);
        psroi_kernel<<<NROIS, 256, 0, stream>>>(feat, rois, om, out);
    } else {
        // fallback fp32 path
        float* zero = (float*)d_ws;
        float* om   = (float*)d_ws + 1024;
        hipMemsetAsync(d_ws, 0, 4096, stream);
        int convThreads = Hh * (Ww / PIX) * OCN;
        conv3x3_kernel<<<(convThreads + 255) / 256, 256, 0, stream>>>(feat, w, zero, om);
        psroi_kernel<<<NROIS, 256, 0, stream>>>(feat, rois, om, out);
    }
}